// Round 4
// baseline (40.892 us; speedup 1.0000x reference)
//
#include <hip/hip_runtime.h>
#include <hip/hip_bf16.h>
#include <math.h>

#define B_ 128
#define IN_ 1024
#define D_ 128
#define H_ 512
#define S_ 256

typedef __attribute__((ext_vector_type(8))) short short8v;
typedef __attribute__((ext_vector_type(8))) unsigned short ushort8v;
typedef __attribute__((ext_vector_type(4))) unsigned short ushort4v;
typedef __attribute__((ext_vector_type(4))) float f32x4;

__device__ __forceinline__ float softplusf(float x) {
  return fmaxf(x, 0.f) + log1pf(expf(-fabsf(x)));
}

__device__ __forceinline__ unsigned short f2bf(float f) {
  unsigned u = __float_as_uint(f);
  unsigned r = (u + 0x7fff + ((u >> 16) & 1)) >> 16;   // RNE
  return (unsigned short)r;
}

// ============ fused prep kernel, block-range dispatch ============
// [0,64)     : pack W1 w-half -> bf16 in MFMA-fragment order Bp[frag][lane][j]
// [64,576)   : log_pwx partial logits  (b x kc-of-4)
// [576,1088) : log_pxw partials        (b x ic-of-4)
// [1088,1344): zb1 + f_zw partials     (b-quad x hc-of-8)
__global__ __launch_bounds__(256) void Kprep(
    const float* __restrict__ x, const float* __restrict__ w,
    const float* __restrict__ z, const float* __restrict__ W,
    const float* __restrict__ cvec, const float* __restrict__ W1,
    const float* __restrict__ b1, const float* __restrict__ W2,
    unsigned short* __restrict__ Bp, float* __restrict__ l2part,
    float* __restrict__ pxw_part, float* __restrict__ zb1,
    float* __restrict__ fzw_part) {
  __shared__ float smem[1024];
  const int blk = blockIdx.x;
  const int t = threadIdx.x;

  if (blk < 64) {
    // ---- pack Bp: Bp[frag*512 + l*8 + j] = bf16(W1w[h][k]),
    // frag=hblk*4+ks, h=hblk*16+(l&15), k=ks*32+(l>>4)*8+j
    const int o = (blk * 256 + t) * 4;
    const int frag = o >> 9;
    const int l = (o >> 3) & 63;
    const int j0 = o & 7;             // 0 or 4
    const int h = (frag >> 2) * 16 + (l & 15);
    const int k0 = (frag & 3) * 32 + ((l >> 4) << 3) + j0;
    const float4 v = *(const float4*)(W1 + (size_t)h * 256 + 128 + k0);
    ushort4v u;
    u[0] = f2bf(v.x); u[1] = f2bf(v.y); u[2] = f2bf(v.z); u[3] = f2bf(v.w);
    *(ushort4v*)(Bp + o) = u;
  } else if (blk < 576) {
    // ---- pwx partial: logits2_part[(b*4+kc)][d]
    const int bb = blk - 64;
    const int b = bb >> 2, kc = bb & 3;
    float* xs = smem;            // 256
    float* p2 = smem + 256;      // 256
    xs[t] = x[b * IN_ + kc * 256 + t];
    __syncthreads();
    const int d = t & 127, ks = t >> 7;
    const float* __restrict__ Wp = W + (size_t)(kc * 256 + ks * 128) * D_ + d;
    float s = 0.f;
    #pragma unroll 8
    for (int i = 0; i < 128; ++i) s = fmaf(xs[ks * 128 + i], Wp[(size_t)i * D_], s);
    p2[ks * 128 + d] = s;
    __syncthreads();
    if (t < 128) l2part[((size_t)b * 4 + kc) * 128 + t] = p2[t] + p2[128 + t];
  } else if (blk < 1088) {
    // ---- pxw partial
    const int bb = blk - 576;
    const int b = bb >> 2, ic = bb & 3;
    float* ws_ = smem;           // 128
    float* red = smem + 128;     // 4
    if (t < 128) ws_[t] = w[b * 128 + t];
    __syncthreads();
    const int i = ic * 256 + t;
    const float4* __restrict__ row = (const float4*)(W + (size_t)i * D_);
    float a0 = 0.f, a1 = 0.f, a2 = 0.f, a3 = 0.f;
    #pragma unroll
    for (int q = 0; q < 32; ++q) {
      const float4 v = row[q];
      a0 = fmaf(v.x, ws_[4 * q + 0], a0);
      a1 = fmaf(v.y, ws_[4 * q + 1], a1);
      a2 = fmaf(v.z, ws_[4 * q + 2], a2);
      a3 = fmaf(v.w, ws_[4 * q + 3], a3);
    }
    const float lg = cvec[i] + ((a0 + a1) + (a2 + a3));
    float term = x[b * IN_ + i] * lg - softplusf(lg);
    #pragma unroll
    for (int o = 32; o > 0; o >>= 1) term += __shfl_down(term, o);
    const int lane = t & 63, wid = t >> 6;
    if (lane == 0) red[wid] = term;
    __syncthreads();
    if (t == 0) pxw_part[b * 4 + ic] = red[0] + red[1] + red[2] + red[3];
  } else {
    // ---- zw: zb1 + fzw partials
    const int bb = blk - 1088;
    const int bq = bb >> 3, hc = bb & 7;
    float* zs  = smem;           // 512
    float* ws2 = smem + 512;     // 512
    for (int e = t; e < 512; e += 256) {
      zs[e]  = z[bq * 512 + e];
      ws2[e] = w[bq * 512 + e];
    }
    __syncthreads();
    const int bs = t >> 6, hl = t & 63;
    const int b = bq * 4 + bs, h = hc * 64 + hl;
    const float4* __restrict__ row = (const float4*)(W1 + (size_t)h * 256);
    float zp = b1[h], wp = 0.f;
    #pragma unroll
    for (int q = 0; q < 32; ++q) {
      const float4 v = row[q];
      zp = fmaf(v.x, zs[bs * 128 + 4 * q + 0], zp);
      zp = fmaf(v.y, zs[bs * 128 + 4 * q + 1], zp);
      zp = fmaf(v.z, zs[bs * 128 + 4 * q + 2], zp);
      zp = fmaf(v.w, zs[bs * 128 + 4 * q + 3], zp);
    }
    #pragma unroll
    for (int q = 32; q < 64; ++q) {
      const float4 v = row[q];
      wp = fmaf(v.x, ws2[bs * 128 + 4 * (q - 32) + 0], wp);
      wp = fmaf(v.y, ws2[bs * 128 + 4 * (q - 32) + 1], wp);
      wp = fmaf(v.z, ws2[bs * 128 + 4 * (q - 32) + 2], wp);
      wp = fmaf(v.w, ws2[bs * 128 + 4 * (q - 32) + 3], wp);
    }
    zb1[(size_t)b * H_ + h] = zp;
    float fp = fmaxf(zp + wp, 0.f) * W2[h];
    #pragma unroll
    for (int o = 1; o < 64; o <<= 1) fp += __shfl_xor(fp, o);
    if (hl == 0) fzw_part[b * 8 + hc] = fp;
  }
}

// ============ main fused kernel: one block per b ============
// 1024 threads = 16 waves; wave wvid: sc=wvid>>2 (s-chunk of 64),
// nh=(wvid>>1)&1 (h half), nth=wvid&1 (h quarter within half).
// Per wave: 4 m-tiles x 8 h-tiles x 4 ks MFMA. Then in-block logsumexp +
// pwx finish + final combine -> out[b].
__global__ __launch_bounds__(1024) void Kmain(
    const float* __restrict__ wt, const unsigned short* __restrict__ Bp,
    const float* __restrict__ zb1, const float* __restrict__ W2,
    const float* __restrict__ b2, const float* __restrict__ l2part,
    const float* __restrict__ bvec, const float* __restrict__ w,
    const float* __restrict__ pxw_part, const float* __restrict__ fzw_part,
    float* __restrict__ out) {
  const int b = blockIdx.x;
  const int t = threadIdx.x;
  const int lane = t & 63, wvid = t >> 6;      // wave 0..15
  const int sc = wvid >> 2, nh = (wvid >> 1) & 1, nth = wvid & 1;

  __shared__ unsigned short atile[256 * 128];  // 64 KB, XOR-swizzled bf16
  __shared__ float zb1s[H_];
  __shared__ float w2s[H_];
  __shared__ float red[16][64];                // 4 KB
  __shared__ float mred[4], ered[4], pred[2], miscs[2];

  if (t < 512) { zb1s[t] = zb1[(size_t)b * H_ + t]; w2s[t] = W2[t]; }

  // stage A: 256 rows x 128 d, fp32 -> bf16, granule swizzle g ^= r&15
  {
    const int r = t >> 2;                      // 0..255
    const int g0 = (t & 3) * 4;
    const float* __restrict__ src = wt + ((size_t)r * B_ + b) * D_;
    #pragma unroll
    for (int gg = 0; gg < 4; ++gg) {
      const int g = g0 + gg;
      const float4 v0 = *(const float4*)(src + g * 8);
      const float4 v1 = *(const float4*)(src + g * 8 + 4);
      ushort8v u;
      u[0] = f2bf(v0.x); u[1] = f2bf(v0.y); u[2] = f2bf(v0.z); u[3] = f2bf(v0.w);
      u[4] = f2bf(v1.x); u[5] = f2bf(v1.y); u[6] = f2bf(v1.z); u[7] = f2bf(v1.w);
      *(ushort8v*)&atile[r * 128 + ((g ^ (r & 15)) << 3)] = u;
    }
  }
  __syncthreads();

  // A fragments: row = sc*64 + m*16 + (lane&15), k = ks*32 + (lane>>4)*8 + j
  short8v afr[4][4];
  #pragma unroll
  for (int m = 0; m < 4; ++m) {
    const int arow = sc * 64 + m * 16 + (lane & 15);
    #pragma unroll
    for (int ks = 0; ks < 4; ++ks) {
      const int g = ks * 4 + (lane >> 4);
      afr[m][ks] = *(const short8v*)&atile[arow * 128 + ((g ^ (arow & 15)) << 3)];
    }
  }

  float fsum[4][4];
  #pragma unroll
  for (int m = 0; m < 4; ++m)
    #pragma unroll
    for (int j = 0; j < 4; ++j) fsum[m][j] = 0.f;

  const int hl = lane & 15;
  #pragma unroll 2
  for (int nt = 0; nt < 8; ++nt) {
    const int hblk = nh * 16 + nth * 8 + nt;   // 0..31
    const int hrow = hblk * 16 + hl;
    f32x4 acc0 = {0.f,0.f,0.f,0.f}, acc1 = {0.f,0.f,0.f,0.f};
    f32x4 acc2 = {0.f,0.f,0.f,0.f}, acc3 = {0.f,0.f,0.f,0.f};
    #pragma unroll
    for (int ks = 0; ks < 4; ++ks) {
      const int frag = hblk * 4 + ks;
      const short8v bfr = *(const short8v*)(Bp + ((size_t)frag << 9) + (lane << 3));
      acc0 = __builtin_amdgcn_mfma_f32_16x16x32_bf16(afr[0][ks], bfr, acc0, 0, 0, 0);
      acc1 = __builtin_amdgcn_mfma_f32_16x16x32_bf16(afr[1][ks], bfr, acc1, 0, 0, 0);
      acc2 = __builtin_amdgcn_mfma_f32_16x16x32_bf16(afr[2][ks], bfr, acc2, 0, 0, 0);
      acc3 = __builtin_amdgcn_mfma_f32_16x16x32_bf16(afr[3][ks], bfr, acc3, 0, 0, 0);
    }
    const float zv = zb1s[hrow], wgt = w2s[hrow];
    #pragma unroll
    for (int j = 0; j < 4; ++j) {
      fsum[0][j] += fmaxf(acc0[j] + zv, 0.f) * wgt;
      fsum[1][j] += fmaxf(acc1[j] + zv, 0.f) * wgt;
      fsum[2][j] += fmaxf(acc2[j] + zv, 0.f) * wgt;
      fsum[3][j] += fmaxf(acc3[j] + zv, 0.f) * wgt;
    }
  }
  // reduce over 16 h-columns (lane bits 0..3)
  #pragma unroll
  for (int m = 0; m < 4; ++m)
    #pragma unroll
    for (int j = 0; j < 4; ++j) {
      float v = fsum[m][j];
      v += __shfl_xor(v, 1); v += __shfl_xor(v, 2);
      v += __shfl_xor(v, 4); v += __shfl_xor(v, 8);
      fsum[m][j] = v;
    }
  if (hl == 0) {
    const int rb = (lane >> 4) * 4;
    #pragma unroll
    for (int m = 0; m < 4; ++m)
      #pragma unroll
      for (int j = 0; j < 4; ++j)
        red[wvid][m * 16 + rb + j] = fsum[m][j];
  }
  __syncthreads();

  // ---- fused finisher ----
  float fval = 0.f;
  if (t < 256) {
    const int sc2 = t >> 6, r = t & 63;
    fval = red[sc2 * 4 + 0][r] + red[sc2 * 4 + 1][r]
         + red[sc2 * 4 + 2][r] + red[sc2 * 4 + 3][r] + b2[0];
    float mm = fval;
    #pragma unroll
    for (int o = 1; o < 64; o <<= 1) mm = fmaxf(mm, __shfl_xor(mm, o));
    if (lane == 0) mred[wvid] = mm;
  } else if (t < 384) {
    // pwx finish: 128 threads (waves 4,5)
    const int d = t - 256;
    float lg = bvec[d];
    #pragma unroll
    for (int kc = 0; kc < 4; ++kc) lg += l2part[((size_t)b * 4 + kc) * 128 + d];
    float term = w[b * 128 + d] * lg - softplusf(lg);
    #pragma unroll
    for (int o = 1; o < 64; o <<= 1) term += __shfl_xor(term, o);
    if (lane == 0) pred[wvid - 4] = term;
  } else if (t == 384) {
    miscs[0] = pxw_part[b * 4] + pxw_part[b * 4 + 1]
             + pxw_part[b * 4 + 2] + pxw_part[b * 4 + 3];
  } else if (t == 385) {
    miscs[1] = fzw_part[b * 8 + 0] + fzw_part[b * 8 + 1] + fzw_part[b * 8 + 2]
             + fzw_part[b * 8 + 3] + fzw_part[b * 8 + 4] + fzw_part[b * 8 + 5]
             + fzw_part[b * 8 + 6] + fzw_part[b * 8 + 7];
  }
  __syncthreads();
  if (t < 256) {
    const float mm = fmaxf(fmaxf(mred[0], mred[1]), fmaxf(mred[2], mred[3]));
    float e = expf(fval - mm);
    #pragma unroll
    for (int o = 1; o < 64; o <<= 1) e += __shfl_xor(e, o);
    if (lane == 0) ered[wvid] = e;
  }
  __syncthreads();
  if (t == 0) {
    const float mm = fmaxf(fmaxf(mred[0], mred[1]), fmaxf(mred[2], mred[3]));
    const float tot = ered[0] + ered[1] + ered[2] + ered[3];
    const float logZ = mm + logf(tot) - logf((float)S_) + (float)D_ * logf(2.f);
    const float pwx = pred[0] + pred[1];
    const float pxw = miscs[0];
    const float fzw = miscs[1] + b2[0];
    const float r_wz = fminf(fzw - logZ, 0.f);
    out[b] = -(pxw - pwx + r_wz);
  }
}

extern "C" void kernel_launch(void* const* d_in, const int* in_sizes, int n_in,
                              void* d_out, int out_size, void* d_ws, size_t ws_size,
                              hipStream_t stream) {
  const float* x    = (const float*)d_in[0];
  // d_in[1] = y, unused
  const float* w    = (const float*)d_in[2];
  const float* z    = (const float*)d_in[3];
  const float* wt   = (const float*)d_in[4];
  const float* W    = (const float*)d_in[5];
  const float* bvec = (const float*)d_in[6];
  const float* cvec = (const float*)d_in[7];
  const float* W1   = (const float*)d_in[8];
  const float* b1   = (const float*)d_in[9];
  const float* W2   = (const float*)d_in[10];
  const float* b2   = (const float*)d_in[11];

  float* ws_f = (float*)d_ws;
  float* zb1            = ws_f;                              // 65536 f
  unsigned short* Bp    = (unsigned short*)(ws_f + 65536);   // 65536 us
  float* l2part         = ws_f + 98304;                      // 65536 f
  float* pxw_part       = ws_f + 163840;                     // 512 f
  float* fzw_part       = ws_f + 164352;                     // 1024 f
  float* out = (float*)d_out;

  hipLaunchKernelGGL(Kprep, dim3(1344), dim3(256), 0, stream,
                     x, w, z, W, cvec, W1, b1, W2, Bp, l2part, pxw_part, zb1, fzw_part);
  hipLaunchKernelGGL(Kmain, dim3(B_), dim3(1024), 0, stream,
                     wt, Bp, zb1, W2, b2, l2part, bvec, w, pxw_part, fzw_part, out);
}

// Round 5
// 36.824 us; speedup vs baseline: 1.1105x; 1.1105x over previous
//
#include <hip/hip_runtime.h>
#include <hip/hip_bf16.h>
#include <math.h>

#define B_ 128
#define IN_ 1024
#define D_ 128
#define H_ 512
#define S_ 256

typedef __attribute__((ext_vector_type(8))) short short8v;
typedef __attribute__((ext_vector_type(8))) unsigned short ushort8v;
typedef __attribute__((ext_vector_type(4))) unsigned short ushort4v;
typedef __attribute__((ext_vector_type(4))) float f32x4;

__device__ __forceinline__ float softplusf(float x) {
  return fmaxf(x, 0.f) + log1pf(expf(-fabsf(x)));
}

__device__ __forceinline__ unsigned short f2bf(float f) {
  unsigned u = __float_as_uint(f);
  unsigned r = (u + 0x7fff + ((u >> 16) & 1)) >> 16;   // RNE
  return (unsigned short)r;
}

// ============ fused prep kernel, block-range dispatch ============
// [0,64)      : pack W1 w-half -> bf16 MFMA-fragment order Bp
// [64,1088)   : log_pwx partial logits  (b x kc-of-8, 128 i-rows each)
// [1088,1600) : log_pxw partials        (b x ic-of-4) — 16-lane/row coalesced
// [1600,1856) : zb1 + f_zw partials     (b-quad x hc-of-8) — 16-lane/row coalesced
__global__ __launch_bounds__(256) void Kprep(
    const float* __restrict__ x, const float* __restrict__ w,
    const float* __restrict__ z, const float* __restrict__ W,
    const float* __restrict__ cvec, const float* __restrict__ W1,
    const float* __restrict__ b1, const float* __restrict__ W2,
    unsigned short* __restrict__ Bp, float* __restrict__ l2part,
    float* __restrict__ pxw_part, float* __restrict__ zb1,
    float* __restrict__ fzw_part) {
  __shared__ float smem[1024];
  const int blk = blockIdx.x;
  const int t = threadIdx.x;

  if (blk < 64) {
    // ---- pack Bp (unchanged, verified): frag=hblk*4+ks, h=hblk*16+(l&15),
    // k=ks*32+(l>>4)*8+j
    const int o = (blk * 256 + t) * 4;
    const int frag = o >> 9;
    const int l = (o >> 3) & 63;
    const int j0 = o & 7;
    const int h = (frag >> 2) * 16 + (l & 15);
    const int k0 = (frag & 3) * 32 + ((l >> 4) << 3) + j0;
    const float4 v = *(const float4*)(W1 + (size_t)h * 256 + 128 + k0);
    ushort4v u;
    u[0] = f2bf(v.x); u[1] = f2bf(v.y); u[2] = f2bf(v.z); u[3] = f2bf(v.w);
    *(ushort4v*)(Bp + o) = u;
  } else if (blk < 1088) {
    // ---- pwx partial: 1024 blocks, (b, kc of 8): 128 i-rows
    const int bb = blk - 64;
    const int b = bb >> 3, kc = bb & 7;
    float* xs = smem;            // 128
    float* p2 = smem + 128;      // 256
    if (t < 128) xs[t] = x[b * IN_ + kc * 128 + t];
    __syncthreads();
    const int d = t & 127, ks = t >> 7;
    const float* __restrict__ Wp = W + (size_t)(kc * 128 + ks * 64) * D_ + d;
    float s = 0.f;
    #pragma unroll 8
    for (int i = 0; i < 64; ++i) s = fmaf(xs[ks * 64 + i], Wp[(size_t)i * D_], s);
    p2[ks * 128 + d] = s;
    __syncthreads();
    if (t < 128) l2part[((size_t)b * 8 + kc) * 128 + t] = p2[t] + p2[128 + t];
  } else if (blk < 1600) {
    // ---- pxw partial: (b, ic of 4), 16 lanes per i-row, coalesced
    const int bb = blk - 1088;
    const int b = bb >> 2, ic = bb & 3;
    float* ws_ = smem;           // 128
    float* red = smem + 128;     // 4
    if (t < 128) ws_[t] = w[b * 128 + t];
    __syncthreads();
    const int chunk = t & 15, rgrp = t >> 4;   // 16 rows per iteration
    float wreg[8];
    #pragma unroll
    for (int j = 0; j < 8; ++j) wreg[j] = ws_[chunk * 8 + j];
    float term = 0.f;
    #pragma unroll 2
    for (int it = 0; it < 16; ++it) {
      const int i = ic * 256 + it * 16 + rgrp;
      const float4* __restrict__ rp = (const float4*)(W + (size_t)i * D_ + chunk * 8);
      const float4 va = rp[0], vb = rp[1];
      float dot = 0.f;
      dot = fmaf(va.x, wreg[0], dot); dot = fmaf(va.y, wreg[1], dot);
      dot = fmaf(va.z, wreg[2], dot); dot = fmaf(va.w, wreg[3], dot);
      dot = fmaf(vb.x, wreg[4], dot); dot = fmaf(vb.y, wreg[5], dot);
      dot = fmaf(vb.z, wreg[6], dot); dot = fmaf(vb.w, wreg[7], dot);
      dot += __shfl_xor(dot, 1); dot += __shfl_xor(dot, 2);
      dot += __shfl_xor(dot, 4); dot += __shfl_xor(dot, 8);
      if (chunk == 0) {
        const float lg = dot + cvec[i];
        term += x[b * IN_ + i] * lg - softplusf(lg);
      }
    }
    #pragma unroll
    for (int o = 32; o > 0; o >>= 1) term += __shfl_down(term, o);
    const int lane = t & 63, wid = t >> 6;
    if (lane == 0) red[wid] = term;
    __syncthreads();
    if (t == 0) pxw_part[b * 4 + ic] = red[0] + red[1] + red[2] + red[3];
  } else {
    // ---- zw: (b-quad, hc of 8), wave = b, 16 lanes per h-row, coalesced
    const int bb = blk - 1600;
    const int bq = bb >> 3, hc = bb & 7;
    float* zs  = smem;           // 512
    float* ws2 = smem + 512;     // 512
    for (int e = t; e < 512; e += 256) {
      zs[e]  = z[bq * 512 + e];
      ws2[e] = w[bq * 512 + e];
    }
    __syncthreads();
    const int bs = t >> 6, lane = t & 63;
    const int c16 = lane & 15, rsub = lane >> 4;
    const int b = bq * 4 + bs;
    float zreg[16];
    #pragma unroll
    for (int j = 0; j < 16; ++j)
      zreg[j] = (c16 < 8) ? zs[bs * 128 + c16 * 16 + j]
                          : ws2[bs * 128 + c16 * 16 - 128 + j];
    float fpacc = 0.f;
    #pragma unroll 2
    for (int it = 0; it < 16; ++it) {
      const int h = hc * 64 + it * 4 + rsub;
      const float4* __restrict__ rp = (const float4*)(W1 + (size_t)h * 256 + c16 * 16);
      float dot = 0.f;
      #pragma unroll
      for (int q = 0; q < 4; ++q) {
        const float4 v = rp[q];
        dot = fmaf(v.x, zreg[4 * q + 0], dot);
        dot = fmaf(v.y, zreg[4 * q + 1], dot);
        dot = fmaf(v.z, zreg[4 * q + 2], dot);
        dot = fmaf(v.w, zreg[4 * q + 3], dot);
      }
      dot += __shfl_xor(dot, 1); dot += __shfl_xor(dot, 2);
      dot += __shfl_xor(dot, 4);
      const float other = __shfl_xor(dot, 8);   // zp-lanes get wp, wp-lanes get zp
      if (c16 == 0) {
        const float zp = dot + b1[h];
        zb1[(size_t)b * H_ + h] = zp;
        fpacc += fmaxf(zp + other, 0.f) * W2[h];
      }
    }
    fpacc += __shfl_xor(fpacc, 16);
    fpacc += __shfl_xor(fpacc, 32);
    if (lane == 0) fzw_part[b * 8 + hc] = fpacc;
  }
}

// ============ main fused kernel: one block per b ============
__global__ __launch_bounds__(1024) void Kmain(
    const float* __restrict__ wt, const unsigned short* __restrict__ Bp,
    const float* __restrict__ zb1, const float* __restrict__ W2,
    const float* __restrict__ b2, const float* __restrict__ l2part,
    const float* __restrict__ bvec, const float* __restrict__ w,
    const float* __restrict__ pxw_part, const float* __restrict__ fzw_part,
    float* __restrict__ out) {
  const int b = blockIdx.x;
  const int t = threadIdx.x;
  const int lane = t & 63, wvid = t >> 6;      // wave 0..15
  const int sc = wvid >> 2, nh = (wvid >> 1) & 1, nth = wvid & 1;

  __shared__ unsigned short atile[256 * 128];  // 64 KB, XOR-swizzled bf16
  __shared__ float zb1s[H_];
  __shared__ float w2s[H_];
  __shared__ float red[16][64];
  __shared__ float mred[4], ered[4], pred[2], miscs[2];

  if (t < 512) { zb1s[t] = zb1[(size_t)b * H_ + t]; w2s[t] = W2[t]; }

  // stage A: 256 rows x 128 d, fp32 -> bf16, granule swizzle g ^= r&15
  {
    const int r = t >> 2;
    const int g0 = (t & 3) * 4;
    const float* __restrict__ src = wt + ((size_t)r * B_ + b) * D_;
    #pragma unroll
    for (int gg = 0; gg < 4; ++gg) {
      const int g = g0 + gg;
      const float4 v0 = *(const float4*)(src + g * 8);
      const float4 v1 = *(const float4*)(src + g * 8 + 4);
      ushort8v u;
      u[0] = f2bf(v0.x); u[1] = f2bf(v0.y); u[2] = f2bf(v0.z); u[3] = f2bf(v0.w);
      u[4] = f2bf(v1.x); u[5] = f2bf(v1.y); u[6] = f2bf(v1.z); u[7] = f2bf(v1.w);
      *(ushort8v*)&atile[r * 128 + ((g ^ (r & 15)) << 3)] = u;
    }
  }
  __syncthreads();

  short8v afr[4][4];
  #pragma unroll
  for (int m = 0; m < 4; ++m) {
    const int arow = sc * 64 + m * 16 + (lane & 15);
    #pragma unroll
    for (int ks = 0; ks < 4; ++ks) {
      const int g = ks * 4 + (lane >> 4);
      afr[m][ks] = *(const short8v*)&atile[arow * 128 + ((g ^ (arow & 15)) << 3)];
    }
  }

  float fsum[4][4];
  #pragma unroll
  for (int m = 0; m < 4; ++m)
    #pragma unroll
    for (int j = 0; j < 4; ++j) fsum[m][j] = 0.f;

  const int hl = lane & 15;
  #pragma unroll 2
  for (int nt = 0; nt < 8; ++nt) {
    const int hblk = nh * 16 + nth * 8 + nt;
    const int hrow = hblk * 16 + hl;
    f32x4 acc0 = {0.f,0.f,0.f,0.f}, acc1 = {0.f,0.f,0.f,0.f};
    f32x4 acc2 = {0.f,0.f,0.f,0.f}, acc3 = {0.f,0.f,0.f,0.f};
    #pragma unroll
    for (int ks = 0; ks < 4; ++ks) {
      const int frag = hblk * 4 + ks;
      const short8v bfr = *(const short8v*)(Bp + ((size_t)frag << 9) + (lane << 3));
      acc0 = __builtin_amdgcn_mfma_f32_16x16x32_bf16(afr[0][ks], bfr, acc0, 0, 0, 0);
      acc1 = __builtin_amdgcn_mfma_f32_16x16x32_bf16(afr[1][ks], bfr, acc1, 0, 0, 0);
      acc2 = __builtin_amdgcn_mfma_f32_16x16x32_bf16(afr[2][ks], bfr, acc2, 0, 0, 0);
      acc3 = __builtin_amdgcn_mfma_f32_16x16x32_bf16(afr[3][ks], bfr, acc3, 0, 0, 0);
    }
    const float zv = zb1s[hrow], wgt = w2s[hrow];
    #pragma unroll
    for (int j = 0; j < 4; ++j) {
      fsum[0][j] += fmaxf(acc0[j] + zv, 0.f) * wgt;
      fsum[1][j] += fmaxf(acc1[j] + zv, 0.f) * wgt;
      fsum[2][j] += fmaxf(acc2[j] + zv, 0.f) * wgt;
      fsum[3][j] += fmaxf(acc3[j] + zv, 0.f) * wgt;
    }
  }
  #pragma unroll
  for (int m = 0; m < 4; ++m)
    #pragma unroll
    for (int j = 0; j < 4; ++j) {
      float v = fsum[m][j];
      v += __shfl_xor(v, 1); v += __shfl_xor(v, 2);
      v += __shfl_xor(v, 4); v += __shfl_xor(v, 8);
      fsum[m][j] = v;
    }
  if (hl == 0) {
    const int rb = (lane >> 4) * 4;
    #pragma unroll
    for (int m = 0; m < 4; ++m)
      #pragma unroll
      for (int j = 0; j < 4; ++j)
        red[wvid][m * 16 + rb + j] = fsum[m][j];
  }
  __syncthreads();

  // ---- fused finisher ----
  float fval = 0.f;
  if (t < 256) {
    const int sc2 = t >> 6, r = t & 63;
    fval = red[sc2 * 4 + 0][r] + red[sc2 * 4 + 1][r]
         + red[sc2 * 4 + 2][r] + red[sc2 * 4 + 3][r] + b2[0];
    float mm = fval;
    #pragma unroll
    for (int o = 1; o < 64; o <<= 1) mm = fmaxf(mm, __shfl_xor(mm, o));
    if (lane == 0) mred[wvid] = mm;
  } else if (t < 384) {
    const int d = t - 256;
    float lg = bvec[d];
    #pragma unroll
    for (int kc = 0; kc < 8; ++kc) lg += l2part[((size_t)b * 8 + kc) * 128 + d];
    float term = w[b * 128 + d] * lg - softplusf(lg);
    #pragma unroll
    for (int o = 1; o < 64; o <<= 1) term += __shfl_xor(term, o);
    if (lane == 0) pred[wvid - 4] = term;
  } else if (t == 384) {
    miscs[0] = pxw_part[b * 4] + pxw_part[b * 4 + 1]
             + pxw_part[b * 4 + 2] + pxw_part[b * 4 + 3];
  } else if (t == 385) {
    miscs[1] = fzw_part[b * 8 + 0] + fzw_part[b * 8 + 1] + fzw_part[b * 8 + 2]
             + fzw_part[b * 8 + 3] + fzw_part[b * 8 + 4] + fzw_part[b * 8 + 5]
             + fzw_part[b * 8 + 6] + fzw_part[b * 8 + 7];
  }
  __syncthreads();
  if (t < 256) {
    const float mm = fmaxf(fmaxf(mred[0], mred[1]), fmaxf(mred[2], mred[3]));
    float e = expf(fval - mm);
    #pragma unroll
    for (int o = 1; o < 64; o <<= 1) e += __shfl_xor(e, o);
    if (lane == 0) ered[wvid] = e;
  }
  __syncthreads();
  if (t == 0) {
    const float mm = fmaxf(fmaxf(mred[0], mred[1]), fmaxf(mred[2], mred[3]));
    const float tot = ered[0] + ered[1] + ered[2] + ered[3];
    const float logZ = mm + logf(tot) - logf((float)S_) + (float)D_ * logf(2.f);
    const float pwx = pred[0] + pred[1];
    const float pxw = miscs[0];
    const float fzw = miscs[1] + b2[0];
    const float r_wz = fminf(fzw - logZ, 0.f);
    out[b] = -(pxw - pwx + r_wz);
  }
}

extern "C" void kernel_launch(void* const* d_in, const int* in_sizes, int n_in,
                              void* d_out, int out_size, void* d_ws, size_t ws_size,
                              hipStream_t stream) {
  const float* x    = (const float*)d_in[0];
  // d_in[1] = y, unused
  const float* w    = (const float*)d_in[2];
  const float* z    = (const float*)d_in[3];
  const float* wt   = (const float*)d_in[4];
  const float* W    = (const float*)d_in[5];
  const float* bvec = (const float*)d_in[6];
  const float* cvec = (const float*)d_in[7];
  const float* W1   = (const float*)d_in[8];
  const float* b1   = (const float*)d_in[9];
  const float* W2   = (const float*)d_in[10];
  const float* b2   = (const float*)d_in[11];

  float* ws_f = (float*)d_ws;
  float* zb1            = ws_f;                              // 65536 f
  unsigned short* Bp    = (unsigned short*)(ws_f + 65536);   // 65536 us (32768 f)
  float* l2part         = ws_f + 98304;                      // 131072 f
  float* pxw_part       = ws_f + 229376;                     // 512 f
  float* fzw_part       = ws_f + 229888;                     // 1024 f
  float* out = (float*)d_out;

  hipLaunchKernelGGL(Kprep, dim3(1856), dim3(256), 0, stream,
                     x, w, z, W, cvec, W1, b1, W2, Bp, l2part, pxw_part, zb1, fzw_part);
  hipLaunchKernelGGL(Kmain, dim3(B_), dim3(1024), 0, stream,
                     wt, Bp, zb1, W2, b2, l2part, bvec, w, pxw_part, fzw_part, out);
}